// Round 1
// baseline (2016.957 us; speedup 1.0000x reference)
//
#include <hip/hip_runtime.h>

typedef _Float16 f16;
typedef _Float16 f16x8 __attribute__((ext_vector_type(8)));
typedef float f32x4 __attribute__((ext_vector_type(4)));

// ---------------- K1: scalar edge pass (sx, cnt) ----------------
__global__ void k_edge_scalar(const int* __restrict__ src, const int* __restrict__ dst,
                              const float* __restrict__ x, float* __restrict__ sx,
                              float* __restrict__ cnt, int E) {
    int stride = gridDim.x * blockDim.x;
    for (int e = blockIdx.x * blockDim.x + threadIdx.x; e < E; e += stride) {
        int s = src[e], d = dst[e];
        atomicAdd(&sx[d], x[s]);
        atomicAdd(&cnt[d], 1.0f);
    }
}

// ---------------- K2: z1 (closed form) -> y_root, y_rel ----------------
// one wave per node; W_root2/W_rel2 staged in LDS
__global__ __launch_bounds__(256) void k_layer1(
    const float* __restrict__ x, const float* __restrict__ sx, const float* __restrict__ cnt,
    const float* __restrict__ Wr1, const float* __restrict__ Wl1, const float* __restrict__ b1,
    const float* __restrict__ Wroot2, const float* __restrict__ Wrel2,
    float* __restrict__ y_root, float* __restrict__ y_rel, int N) {
    __shared__ float Wr2s[128 * 64];
    __shared__ float Wl2s[128 * 64];
    __shared__ float p1s[3 * 128];
    __shared__ float z1s[4][128];
    int tid = threadIdx.x;
    for (int i = tid; i < 128 * 64; i += 256) { Wr2s[i] = Wroot2[i]; Wl2s[i] = Wrel2[i]; }
    for (int i = tid; i < 128; i += 256) { p1s[i] = Wr1[i]; p1s[128 + i] = Wl1[i]; p1s[256 + i] = b1[i]; }
    __syncthreads();
    int w = tid >> 6, lane = tid & 63;
    int perIter = gridDim.x * 4;
    int iters = (N + perIter - 1) / perIter;
    for (int it = 0; it < iters; ++it) {
        int node = it * perIter + blockIdx.x * 4 + w;
        bool valid = node < N;
        float a = 0.f, m = 0.f;
        if (valid) {
            a = x[node];
            m = sx[node] / fmaxf(cnt[node], 1.0f);
        }
        float z_a = fmaxf(a * p1s[lane] + m * p1s[128 + lane] + p1s[256 + lane], 0.0f);
        float z_b = fmaxf(a * p1s[lane + 64] + m * p1s[128 + lane + 64] + p1s[256 + lane + 64], 0.0f);
        z1s[w][lane] = z_a;
        z1s[w][lane + 64] = z_b;
        __syncthreads();
        float yr = 0.f, yl = 0.f;
        #pragma unroll 4
        for (int c = 0; c < 128; ++c) {
            float zc = z1s[w][c];
            yr += zc * Wr2s[c * 64 + lane];
            yl += zc * Wl2s[c * 64 + lane];
        }
        if (valid) {
            y_root[(size_t)node * 64 + lane] = yr;
            y_rel[(size_t)node * 64 + lane] = yl;
        }
        __syncthreads();
    }
}

// ---------------- K3: scatter-add y_rel[src] into aggY[dst] ----------------
__global__ void k_scatter(const int* __restrict__ src, const int* __restrict__ dst,
                          const float* __restrict__ y_rel, float* __restrict__ aggY, int E) {
    int lane = threadIdx.x & 63;
    int wid = (blockIdx.x * blockDim.x + threadIdx.x) >> 6;
    int nw = (gridDim.x * blockDim.x) >> 6;
    for (int e = wid; e < E; e += nw) {
        int s = src[e], d = dst[e];
        float v = y_rel[(size_t)s * 64 + lane];
        atomicAdd(&aggY[(size_t)d * 64 + lane], v);
    }
}

// ---------------- K4: z2 = relu(y_root + aggY/cnt + b2) ----------------
__global__ void k_z2(const float* __restrict__ y_root, const float* __restrict__ aggY,
                     const float* __restrict__ cnt, const float* __restrict__ b2,
                     float* __restrict__ z2, int N) {
    int stride = gridDim.x * blockDim.x;
    int total = N * 64;
    for (int t = blockIdx.x * blockDim.x + threadIdx.x; t < total; t += stride) {
        int node = t >> 6, k = t & 63;
        float c = fmaxf(cnt[node], 1.0f);
        float v = y_root[t] + aggY[t] / c + b2[k];
        z2[t] = fmaxf(v, 0.0f);
    }
}

// ---------------- K5: nrep_f16[e][k] = z2[s][k]*z2[d][k] ----------------
__global__ void k_nrep(const int* __restrict__ es, const int* __restrict__ ed,
                       const float* __restrict__ z2, f16* __restrict__ nrep, int E) {
    int lane = threadIdx.x & 63;
    int wid = (blockIdx.x * blockDim.x + threadIdx.x) >> 6;
    int nw = (gridDim.x * blockDim.x) >> 6;
    for (int e = wid; e < E; e += nw) {
        int s = es[e], d = ed[e];
        float v = z2[(size_t)s * 64 + lane] * z2[(size_t)d * 64 + lane];
        nrep[(size_t)e * 64 + lane] = (f16)v;
    }
}

// ---------------- K5b: W_lin1 -> f16, transposed, chunked [26][128][32] ----------------
__global__ void k_wt(const float* __restrict__ W1, f16* __restrict__ Wt, int total) {
    int t = blockIdx.x * blockDim.x + threadIdx.x;
    if (t >= total) return;
    int c = t & 31, n = (t >> 5) & 127, kk = t >> 12;
    int k = kk * 32 + c;
    Wt[t] = (f16)W1[k * 128 + n];
}

// ---------------- K6: decode GEMM + MLP head + softmax ----------------
#define ASTR 40  // 32 + 8 pad halves; row stride 80B (16B aligned)

__device__ inline f16x8 cvt8(float4 a, float4 b) {
    f16x8 r;
    r[0] = (f16)a.x; r[1] = (f16)a.y; r[2] = (f16)a.z; r[3] = (f16)a.w;
    r[4] = (f16)b.x; r[5] = (f16)b.y; r[6] = (f16)b.z; r[7] = (f16)b.w;
    return r;
}

__global__ __launch_bounds__(256) void k_decode(
    const f16* __restrict__ nrep, const float* __restrict__ ea,
    const f16* __restrict__ Wt, const float* __restrict__ bl1,
    const float* __restrict__ W2, const float* __restrict__ bl2,
    float* __restrict__ out, int E) {
    __shared__ char smem[128 * 136 * 2];          // K-loop: At(10240)+Bt(10240); epilogue: H (34816)
    __shared__ float W2s[128 * 5];
    __shared__ float b1s[128];
    __shared__ float b2s[5];
    f16* At = (f16*)smem;                // [128][ASTR]
    f16* Bt = (f16*)(smem + 10240);      // [128][ASTR]
    f16* H = (f16*)smem;                 // [128][136], aliases At/Bt after the loop

    int tid = threadIdx.x;
    for (int i = tid; i < 640; i += 256) W2s[i] = W2[i];
    if (tid < 128) b1s[tid] = bl1[tid];
    if (tid < 5) b2s[tid] = bl2[tid];

    int blockRow = blockIdx.x;
    int r = tid >> 1;
    int ch = (tid & 1) << 4;  // 0 or 16 halves
    int e = blockRow * 128 + r;
    int ec = (e < E) ? e : (E - 1);

    const int w = tid >> 6, l = tid & 63;
    const int wr = w >> 1, wc = w & 1;
    const int lrow = l & 15, kb = (l >> 4) * 8;

    f32x4 acc[4][4] = {};

    for (int kk = 0; kk < 26; ++kk) {
        f16x8 a0, a1;
        if (kk < 2) {
            const f16x8* p = (const f16x8*)(nrep + (size_t)ec * 64 + kk * 32 + ch);
            a0 = p[0]; a1 = p[1];
        } else {
            const float4* p = (const float4*)(ea + (size_t)ec * 768 + (kk - 2) * 32 + ch);
            float4 v0 = p[0], v1 = p[1], v2 = p[2], v3 = p[3];
            a0 = cvt8(v0, v1);
            a1 = cvt8(v2, v3);
        }
        *(f16x8*)&At[r * ASTR + ch] = a0;
        *(f16x8*)&At[r * ASTR + ch + 8] = a1;
        const f16x8* q = (const f16x8*)(Wt + kk * 4096 + r * 32 + ch);
        *(f16x8*)&Bt[r * ASTR + ch] = q[0];
        *(f16x8*)&Bt[r * ASTR + ch + 8] = q[1];
        __syncthreads();
        f16x8 af[4], bf[4];
        #pragma unroll
        for (int m = 0; m < 4; ++m)
            af[m] = *(const f16x8*)&At[(wr * 64 + m * 16 + lrow) * ASTR + kb];
        #pragma unroll
        for (int n = 0; n < 4; ++n)
            bf[n] = *(const f16x8*)&Bt[(wc * 64 + n * 16 + lrow) * ASTR + kb];
        #pragma unroll
        for (int m = 0; m < 4; ++m)
            #pragma unroll
            for (int n = 0; n < 4; ++n)
                acc[m][n] = __builtin_amdgcn_mfma_f32_16x16x32_f16(af[m], bf[n], acc[m][n], 0, 0, 0);
        __syncthreads();
    }

    // epilogue: h = relu(acc + b1) -> H (f16) in LDS
    #pragma unroll
    for (int m = 0; m < 4; ++m) {
        #pragma unroll
        for (int n = 0; n < 4; ++n) {
            #pragma unroll
            for (int j = 0; j < 4; ++j) {
                int row = wr * 64 + m * 16 + (l >> 4) * 4 + j;
                int col = wc * 64 + n * 16 + (l & 15);
                float h = acc[m][n][j] + b1s[col];
                H[row * 136 + col] = (f16)fmaxf(h, 0.0f);
            }
        }
    }
    __syncthreads();

    // head: logits = h @ W2 + b2, softmax; 2 threads per row
    int rr = tid >> 1, half = tid & 1;
    int cbase = half * 64;
    float lg0 = 0, lg1 = 0, lg2 = 0, lg3 = 0, lg4 = 0;
    #pragma unroll 4
    for (int c = 0; c < 64; ++c) {
        float hv = (float)H[rr * 136 + cbase + c];
        const float* wrow = &W2s[(cbase + c) * 5];
        lg0 += hv * wrow[0]; lg1 += hv * wrow[1]; lg2 += hv * wrow[2];
        lg3 += hv * wrow[3]; lg4 += hv * wrow[4];
    }
    lg0 += __shfl_xor(lg0, 1); lg1 += __shfl_xor(lg1, 1); lg2 += __shfl_xor(lg2, 1);
    lg3 += __shfl_xor(lg3, 1); lg4 += __shfl_xor(lg4, 1);
    int eo = blockRow * 128 + rr;
    if (half == 0 && eo < E) {
        lg0 += b2s[0]; lg1 += b2s[1]; lg2 += b2s[2]; lg3 += b2s[3]; lg4 += b2s[4];
        float mx = fmaxf(fmaxf(fmaxf(lg0, lg1), fmaxf(lg2, lg3)), lg4);
        float p0 = expf(lg0 - mx), p1 = expf(lg1 - mx), p2 = expf(lg2 - mx);
        float p3 = expf(lg3 - mx), p4 = expf(lg4 - mx);
        float inv = 1.0f / (p0 + p1 + p2 + p3 + p4);
        float* o = out + (size_t)eo * 5;
        o[0] = p0 * inv; o[1] = p1 * inv; o[2] = p2 * inv; o[3] = p3 * inv; o[4] = p4 * inv;
    }
}

// ---------------- launch ----------------
extern "C" void kernel_launch(void* const* d_in, const int* in_sizes, int n_in,
                              void* d_out, int out_size, void* d_ws, size_t ws_size,
                              hipStream_t stream) {
    const float* x      = (const float*)d_in[0];
    const int*   tei    = (const int*)d_in[1];
    const int*   ei     = (const int*)d_in[2];
    const float* ea     = (const float*)d_in[3];
    const float* Wr1    = (const float*)d_in[4];
    const float* Wl1    = (const float*)d_in[5];
    const float* b1     = (const float*)d_in[6];
    const float* Wroot2 = (const float*)d_in[7];
    const float* Wrel2  = (const float*)d_in[8];
    const float* b2     = (const float*)d_in[9];
    const float* W1     = (const float*)d_in[10];
    const float* bl1    = (const float*)d_in[11];
    const float* W2     = (const float*)d_in[12];
    const float* bl2    = (const float*)d_in[13];
    float* out = (float*)d_out;

    int N   = in_sizes[0];
    int Etr = in_sizes[1] / 2;
    int Ed  = in_sizes[2] / 2;
    const int* src_tr = tei;
    const int* dst_tr = tei + Etr;
    const int* es = ei;
    const int* edst = ei + Ed;

    char* ws = (char*)d_ws;
    size_t off = 0;
    auto alloc = [&](size_t b) { size_t r = off; off = (off + b + 511) & ~(size_t)511; return r; };
    size_t cntO = alloc((size_t)N * 4);
    size_t sxO  = alloc((size_t)N * 4);
    size_t aggO = alloc((size_t)N * 64 * 4);
    size_t zeroSpan = off;  // cnt+sx+aggY zeroed in one memset
    size_t yrO  = alloc((size_t)N * 64 * 4);
    size_t ylO  = alloc((size_t)N * 64 * 4);
    size_t z2O  = alloc((size_t)N * 64 * 4);
    size_t wtO  = alloc((size_t)26 * 128 * 32 * 2);
    size_t nrO  = aggO;  // nrep aliases aggY (dead after k_z2)

    float* cnt   = (float*)(ws + cntO);
    float* sx    = (float*)(ws + sxO);
    float* aggY  = (float*)(ws + aggO);
    float* yroot = (float*)(ws + yrO);
    float* yrel  = (float*)(ws + ylO);
    float* z2    = (float*)(ws + z2O);
    f16*   Wt    = (f16*)(ws + wtO);
    f16*   nrep  = (f16*)(ws + nrO);

    hipMemsetAsync(ws, 0, zeroSpan, stream);

    k_edge_scalar<<<2048, 256, 0, stream>>>(src_tr, dst_tr, x, sx, cnt, Etr);
    k_layer1<<<1024, 256, 0, stream>>>(x, sx, cnt, Wr1, Wl1, b1, Wroot2, Wrel2, yroot, yrel, N);
    k_scatter<<<8192, 256, 0, stream>>>(src_tr, dst_tr, yrel, aggY, Etr);
    k_z2<<<4096, 256, 0, stream>>>(yroot, aggY, cnt, b2, z2, N);
    k_nrep<<<4096, 256, 0, stream>>>(es, edst, z2, nrep, Ed);
    k_wt<<<(26 * 128 * 32 + 255) / 256, 256, 0, stream>>>(W1, Wt, 26 * 128 * 32);
    k_decode<<<(Ed + 127) / 128, 256, 0, stream>>>(nrep, ea, Wt, bl1, W2, bl2, out, Ed);
}